// Round 4
// baseline (1166.611 us; speedup 1.0000x reference)
//
#include <hip/hip_runtime.h>
#include <stdint.h>

typedef unsigned short u16;
typedef short v8s __attribute__((ext_vector_type(8)));
typedef float v4f __attribute__((ext_vector_type(4)));

typedef __attribute__((address_space(1))) uint32_t g_u32;
typedef __attribute__((address_space(3))) uint32_t l_u32;

// async global->LDS, 16B per lane; LDS dest = wave-uniform base + lane*16
__device__ __forceinline__ void glds16(const void* g, void* l) {
    __builtin_amdgcn_global_load_lds((const g_u32*)g, (l_u32*)l, 16, 0, 0);
}

// scalar fp32 -> bf16, round-to-nearest-even
__device__ __forceinline__ u16 f2b(float f) {
    uint32_t u = __builtin_bit_cast(uint32_t, f);
    u += 0x7FFFu + ((u >> 16) & 1u);
    return (u16)(u >> 16);
}

// pack two fp32 -> two bf16 in one u32 (round-half-up)
__device__ __forceinline__ uint32_t pk2(float a, float b) {
    uint32_t ua = __builtin_bit_cast(uint32_t, a) + 0x8000u;
    uint32_t ub = __builtin_bit_cast(uint32_t, b) + 0x8000u;
    return __builtin_amdgcn_perm(ub, ua, 0x07060302u);  // lo = ua.hi16, hi = ub.hi16
}

#define MTOT  32768
#define HDIM  768
#define KDIM  2000
#define KPAD  2016

// ---------------- K0: convert weights to bf16 (proj_w padded K 2000->2016, zeros) -------
__global__ __launch_bounds__(256) void cvt_weights(
    const float* __restrict__ pw, const float* __restrict__ nw,
    u16* __restrict__ Wb, u16* __restrict__ NWb)
{
    const int h = blockIdx.x;  // 768 blocks
    const float* src = pw + (size_t)h * KDIM;
    u16* dst = Wb + (size_t)h * KPAD;
    for (int k = threadIdx.x; k < KPAD; k += 256)
        dst[k] = (k < KDIM) ? f2b(src[k]) : (u16)0;
    const float* s2 = nw + (size_t)h * HDIM;
    u16* d2 = NWb + (size_t)h * HDIM;
    for (int k = threadIdx.x; k < HDIM; k += 256)
        d2[k] = f2b(s2[k]);
}

// ---------------- K1: GEMM1 full-N strip: x[m_panel, 0:768] = A . Wb^T + bias + gathers -
// Block = 128 m-rows x ALL 768 n-cols, 1024 threads (16 waves, 2m x 4n... 2m x 8n),
// wave = 64x96, acc = 4x6 fragments (96 VGPR). A fetched from HBM EXACTLY ONCE.
// 2-slot LDS (A bf16 8KB + B 48KB per slot = 112 KB), counted vmcnt FIFO:
// per wave per slot: 1 A reg-load (fp32->pk2->ds_write, write-late) + 3 B glds.
// Tail k>=2000: A source clamped (garbage), Wb zero-padded -> contributes 0.
__global__ __launch_bounds__(1024) void gemm1(
    const float* __restrict__ A, const u16* __restrict__ Wb,
    const float* __restrict__ pb,
    const int* __restrict__ i_ty, const int* __restrict__ i_la,
    const int* __restrict__ i_op, const int* __restrict__ i_in, const int* __restrict__ i_ou,
    const float* __restrict__ te, const float* __restrict__ le, const float* __restrict__ oe,
    const float* __restrict__ ie, const float* __restrict__ ooe,
    u16* __restrict__ Xb)
{
    __shared__ __align__(16) u16 As[2][128 * 32];  // 2 x  8 KB bf16
    __shared__ __align__(16) u16 Bs[2][768 * 32];  // 2 x 48 KB bf16 (112 KB total)

    const int tid = threadIdx.x;
    const int w = tid >> 6, lane = tid & 63;
    const int lm = lane & 15, quad = lane >> 4;
    const int wm = (w >> 3) * 64, wn = (w & 7) * 96;
    const int m_base = blockIdx.x * 128;  // 256 blocks, one m-panel each

    // A: lane covers fp32 chunk cA of row rA (linear coalesced 128B rows).
    // ds_write scatters into the B-compatible XOR layout (16B chunk p holds k-chunk
    // p^((r>>1)&3)), so fragment reads are identical for A and B.
    const int rA = w * 8 + (lane >> 3);   // 0..127
    const int cA = lane & 7;              // fp32 16B chunk 0..7
    const float* aRow = A + (size_t)(m_base + rA) * KDIM;
    const int aW = rA * 32 + (((cA >> 1) ^ ((rA >> 1) & 3)) << 3) + ((cA & 1) << 2);  // u16 idx

    // B: 3 glds/wave, 16 rows each (rows = n of Wb). glds dest linear, source XOR'd.
    const u16* bSrc[3];
    int bDst[3];
#pragma unroll
    for (int t = 0; t < 3; t++) {
        const int rB = w * 48 + t * 16 + (lane >> 2);
        const int cB = (lane & 3) ^ ((rB >> 1) & 3);
        bSrc[t] = Wb + (size_t)rB * KPAD + cB * 8;
        bDst[t] = (w * 48 + t * 16) * 32;
    }

    v4f acc[4][6];
#pragma unroll
    for (int i = 0; i < 4; i++)
#pragma unroll
        for (int j = 0; j < 6; j++) acc[i][j] = (v4f){0.f, 0.f, 0.f, 0.f};

    auto lda = [&](int kb) -> float4 {
        int kf = kb * 32 + cA * 4;
        kf = (kf > 1996) ? 1996 : kf;     // clamp tail: garbage * 0-padded Wb
        return *(const float4*)(aRow + kf);
    };
    auto wrA = [&](float4 a, int sl) {
        uint2 p;
        p.x = pk2(a.x, a.y);
        p.y = pk2(a.z, a.w);
        *(uint2*)&As[sl][aW] = p;         // 8B ds_write, swizzled scatter
    };
    auto issueB = [&](int kb) {
        const int sl = kb & 1;
#pragma unroll
        for (int t = 0; t < 3; t++)
            glds16(bSrc[t] + kb * 32, &Bs[sl][bDst[t]]);
    };
    auto compute = [&](int kb) {
        const int sl = kb & 1;
        v8s af[4], bf[6];
#pragma unroll
        for (int i = 0; i < 4; i++) {
            const int r = wm + i * 16 + lm;
            af[i] = *(const v8s*)&As[sl][r * 32 + ((quad ^ ((r >> 1) & 3)) << 3)];
        }
#pragma unroll
        for (int j = 0; j < 6; j++) {
            const int r = wn + j * 16 + lm;
            bf[j] = *(const v8s*)&Bs[sl][r * 32 + ((quad ^ ((r >> 1) & 3)) << 3)];
        }
#pragma unroll
        for (int i = 0; i < 4; i++)
#pragma unroll
            for (int j = 0; j < 6; j++)
                acc[i][j] = __builtin_amdgcn_mfma_f32_16x16x32_bf16(af[i], bf[j], acc[i][j], 0, 0, 0);
    };

    // ---- prologue: slots 0,1 in flight. FIFO: {A0, B0x3, A1, B1x3} ----
    float4 aP = lda(0);
    __builtin_amdgcn_sched_barrier(0);
    issueB(0);
    float4 aN = lda(1);
    __builtin_amdgcn_sched_barrier(0);
    issueB(1);
    asm volatile("s_waitcnt vmcnt(7)" ::: "memory");   // A0 done
    wrA(aP, 0);
    aP = aN;

    // ---- main: 63 K-steps. Steady FIFO at top(kb): {B(kb)x3, A(kb+1), B(kb+1)x3} ----
#pragma unroll 2
    for (int kb = 0; kb < 61; ++kb) {
        asm volatile("s_waitcnt vmcnt(4)" ::: "memory");   // B(kb) done
        asm volatile("s_waitcnt lgkmcnt(0)" ::: "memory"); // own A ds_write visible
        __builtin_amdgcn_s_barrier();
        __builtin_amdgcn_sched_barrier(0);
        compute(kb);
        __builtin_amdgcn_sched_barrier(0);
        __builtin_amdgcn_s_barrier();                      // slot kb&1 free for reuse
        aN = lda(kb + 2);
        __builtin_amdgcn_sched_barrier(0);
        issueB(kb + 2);
        asm volatile("s_waitcnt vmcnt(7)" ::: "memory");   // A(kb+1) done
        wrA(aP, (kb + 1) & 1);
        aP = aN;
    }
    // kb = 61
    asm volatile("s_waitcnt vmcnt(4)" ::: "memory");
    asm volatile("s_waitcnt lgkmcnt(0)" ::: "memory");
    __builtin_amdgcn_s_barrier();
    __builtin_amdgcn_sched_barrier(0);
    compute(61);
    __builtin_amdgcn_sched_barrier(0);
    __builtin_amdgcn_s_barrier();
    asm volatile("s_waitcnt vmcnt(3)" ::: "memory");       // A62 done
    wrA(aP, 0);
    // kb = 62
    asm volatile("s_waitcnt vmcnt(0)" ::: "memory");
    asm volatile("s_waitcnt lgkmcnt(0)" ::: "memory");
    __builtin_amdgcn_s_barrier();
    __builtin_amdgcn_sched_barrier(0);
    compute(62);

    // epilogue: + proj_b + 5 table gathers, write bf16 x
#pragma unroll
    for (int i = 0; i < 4; i++) {
#pragma unroll
        for (int r = 0; r < 4; r++) {
            const int row = m_base + wm + i * 16 + quad * 4 + r;
            const int ty = i_ty[row], la = i_la[row], op = i_op[row];
            const int di = i_in[row], doo = i_ou[row];
            const float* pte = te + (size_t)ty * HDIM;
            const float* ple = le + (size_t)la * HDIM;
            const float* poe = oe + (size_t)op * HDIM;
            const float* pie = ie + (size_t)di * HDIM;
            const float* pou = ooe + (size_t)doo * HDIM;
            u16* orow = Xb + (size_t)row * HDIM;
#pragma unroll
            for (int j = 0; j < 6; j++) {
                const int col = wn + j * 16 + lm;
                float v = acc[i][j][r] + pb[col] + pte[col] + ple[col] + poe[col] + pie[col] + pou[col];
                orow[col] = f2b(v);
            }
        }
    }
}

// ---------------- K2: GEMM2 full-N strip: y[m_panel, 0:768] = xb . NWb^T + neg_b --------
// Same template; A = Xb already bf16 -> all-glds staging (4 glds/wave/slot).
// A tile 8KB covered by waves 0..7; waves 8..15 duplicate (same src, same dest,
// identical bytes -> benign) to keep vmcnt uniform across waves.
__global__ __launch_bounds__(1024) void gemm2(
    const u16* __restrict__ Xb, const u16* __restrict__ NWb,
    const float* __restrict__ nb, u16* __restrict__ Yb)
{
    __shared__ __align__(16) u16 As[2][128 * 32];  // 2 x  8 KB
    __shared__ __align__(16) u16 Bs[2][768 * 32];  // 2 x 48 KB

    const int tid = threadIdx.x;
    const int w = tid >> 6, lane = tid & 63;
    const int lm = lane & 15, quad = lane >> 4;
    const int wm = (w >> 3) * 64, wn = (w & 7) * 96;
    const int m_base = blockIdx.x * 128;

    const int rA = (w & 7) * 16 + (lane >> 2);
    const int cA = (lane & 3) ^ ((rA >> 1) & 3);
    const u16* aSrc = Xb + (size_t)(m_base + rA) * HDIM + cA * 8;
    const int aDst = ((w & 7) * 16) * 32;

    const u16* bSrc[3];
    int bDst[3];
#pragma unroll
    for (int t = 0; t < 3; t++) {
        const int rB = w * 48 + t * 16 + (lane >> 2);
        const int cB = (lane & 3) ^ ((rB >> 1) & 3);
        bSrc[t] = NWb + (size_t)rB * HDIM + cB * 8;
        bDst[t] = (w * 48 + t * 16) * 32;
    }

    v4f acc[4][6];
#pragma unroll
    for (int i = 0; i < 4; i++)
#pragma unroll
        for (int j = 0; j < 6; j++) acc[i][j] = (v4f){0.f, 0.f, 0.f, 0.f};

    auto issue = [&](int kb) {
        const int sl = kb & 1;
        glds16(aSrc + kb * 32, &As[sl][aDst]);
#pragma unroll
        for (int t = 0; t < 3; t++)
            glds16(bSrc[t] + kb * 32, &Bs[sl][bDst[t]]);
    };
    auto compute = [&](int kb) {
        const int sl = kb & 1;
        v8s af[4], bf[6];
#pragma unroll
        for (int i = 0; i < 4; i++) {
            const int r = wm + i * 16 + lm;
            af[i] = *(const v8s*)&As[sl][r * 32 + ((quad ^ ((r >> 1) & 3)) << 3)];
        }
#pragma unroll
        for (int j = 0; j < 6; j++) {
            const int r = wn + j * 16 + lm;
            bf[j] = *(const v8s*)&Bs[sl][r * 32 + ((quad ^ ((r >> 1) & 3)) << 3)];
        }
#pragma unroll
        for (int i = 0; i < 4; i++)
#pragma unroll
            for (int j = 0; j < 6; j++)
                acc[i][j] = __builtin_amdgcn_mfma_f32_16x16x32_bf16(af[i], bf[j], acc[i][j], 0, 0, 0);
    };

    issue(0);
    issue(1);

    // 24 K-steps; steady FIFO at top(kb): {slot(kb)x4, slot(kb+1)x4}
#pragma unroll 2
    for (int kb = 0; kb < 22; ++kb) {
        asm volatile("s_waitcnt vmcnt(4)" ::: "memory");
        __builtin_amdgcn_s_barrier();
        __builtin_amdgcn_sched_barrier(0);
        compute(kb);
        __builtin_amdgcn_sched_barrier(0);
        __builtin_amdgcn_s_barrier();
        issue(kb + 2);
    }
    asm volatile("s_waitcnt vmcnt(4)" ::: "memory");
    __builtin_amdgcn_s_barrier();
    __builtin_amdgcn_sched_barrier(0);
    compute(22);
    __builtin_amdgcn_sched_barrier(0);
    __builtin_amdgcn_s_barrier();
    asm volatile("s_waitcnt vmcnt(0)" ::: "memory");
    __builtin_amdgcn_s_barrier();
    __builtin_amdgcn_sched_barrier(0);
    compute(23);

#pragma unroll
    for (int i = 0; i < 4; i++) {
#pragma unroll
        for (int r = 0; r < 4; r++) {
            const int row = m_base + wm + i * 16 + quad * 4 + r;
            u16* orow = Yb + (size_t)row * HDIM;
#pragma unroll
            for (int j = 0; j < 6; j++) {
                const int col = wn + j * 16 + lm;
                orow[col] = f2b(acc[i][j][r] + nb[col]);
            }
        }
    }
}

// ---------------- K3: select (negs) + LayerNorm, one wave per row -----------------------
__global__ __launch_bounds__(256) void ln_k(
    const u16* __restrict__ Xb, const u16* __restrict__ Yb,
    const int* __restrict__ negs,
    const float* __restrict__ g, const float* __restrict__ b,
    float* __restrict__ out)
{
    const int w = threadIdx.x >> 6, lane = threadIdx.x & 63;
    const int row = blockIdx.x * 4 + w;
    const u16* src = ((negs[row] == 1) ? Yb : Xb) + (size_t)row * HDIM;

    float v[12];
    float s = 0.f, ss = 0.f;
#pragma unroll
    for (int p = 0; p < 3; p++) {
        uint2 u = *(const uint2*)(src + (p * 64 + lane) * 4);
        float f0 = __builtin_bit_cast(float, u.x << 16);
        float f1 = __builtin_bit_cast(float, u.x & 0xFFFF0000u);
        float f2 = __builtin_bit_cast(float, u.y << 16);
        float f3 = __builtin_bit_cast(float, u.y & 0xFFFF0000u);
        v[p * 4 + 0] = f0; v[p * 4 + 1] = f1; v[p * 4 + 2] = f2; v[p * 4 + 3] = f3;
        s += f0 + f1 + f2 + f3;
        ss += f0 * f0 + f1 * f1 + f2 * f2 + f3 * f3;
    }
#pragma unroll
    for (int off = 1; off < 64; off <<= 1) {
        s += __shfl_xor(s, off);
        ss += __shfl_xor(ss, off);
    }
    const float mean = s * (1.f / (float)HDIM);
    const float var = ss * (1.f / (float)HDIM) - mean * mean;
    const float rs = rsqrtf(var + 1e-12f);

    float* orow = out + (size_t)row * HDIM;
#pragma unroll
    for (int p = 0; p < 3; p++) {
        const int c0 = (p * 64 + lane) * 4;
        float4 gg = *(const float4*)(g + c0);
        float4 bb = *(const float4*)(b + c0);
        float4 o;
        o.x = (v[p * 4 + 0] - mean) * rs * gg.x + bb.x;
        o.y = (v[p * 4 + 1] - mean) * rs * gg.y + bb.y;
        o.z = (v[p * 4 + 2] - mean) * rs * gg.z + bb.z;
        o.w = (v[p * 4 + 3] - mean) * rs * gg.w + bb.w;
        *(float4*)(orow + c0) = o;
    }
}

extern "C" void kernel_launch(void* const* d_in, const int* in_sizes, int n_in,
                              void* d_out, int out_size, void* d_ws, size_t ws_size,
                              hipStream_t stream) {
    (void)in_sizes; (void)n_in; (void)out_size; (void)ws_size;
    const float* A   = (const float*)d_in[0];
    const int* i_ty  = (const int*)d_in[1];
    const int* i_la  = (const int*)d_in[2];
    const int* i_op  = (const int*)d_in[3];
    const int* i_in  = (const int*)d_in[4];
    const int* i_ou  = (const int*)d_in[5];
    const int* negs  = (const int*)d_in[6];
    const float* te  = (const float*)d_in[7];
    const float* le  = (const float*)d_in[8];
    const float* oe  = (const float*)d_in[9];
    const float* ie  = (const float*)d_in[10];
    const float* ooe = (const float*)d_in[11];
    const float* pw  = (const float*)d_in[12];
    const float* pb  = (const float*)d_in[13];
    const float* nw  = (const float*)d_in[14];
    const float* nb  = (const float*)d_in[15];
    const float* lng = (const float*)d_in[16];
    const float* lnb = (const float*)d_in[17];
    float* out = (float*)d_out;

    // workspace layout (total ~100.1 MiB)
    char* ws = (char*)d_ws;
    u16* Wb  = (u16*)ws;                                   // 768*2016*2  = 3,096,576
    u16* NWb = (u16*)(ws + 3096576);                       // 768*768*2   = 1,179,648
    u16* Xb  = (u16*)(ws + 3096576 + 1179648);             // 32768*768*2 = 50,331,648
    u16* Yb  = (u16*)(ws + 3096576 + 1179648 + 50331648);  // 50,331,648

    cvt_weights<<<768, 256, 0, stream>>>(pw, nw, Wb, NWb);
    gemm1<<<256, 1024, 0, stream>>>(A, Wb, pb, i_ty, i_la, i_op, i_in, i_ou,
                                    te, le, oe, ie, ooe, Xb);
    gemm2<<<256, 1024, 0, stream>>>(Xb, NWb, nb, Yb);
    ln_k<<<8192, 256, 0, stream>>>(Xb, Yb, negs, lng, lnb, out);
}

// Round 5
// 735.106 us; speedup vs baseline: 1.5870x; 1.5870x over previous
//
#include <hip/hip_runtime.h>
#include <stdint.h>

typedef unsigned short u16;
typedef short v8s __attribute__((ext_vector_type(8)));
typedef float v4f __attribute__((ext_vector_type(4)));

typedef __attribute__((address_space(1))) uint32_t g_u32;
typedef __attribute__((address_space(3))) uint32_t l_u32;

// async global->LDS, 16B per lane; LDS dest = wave-uniform base + lane*16
__device__ __forceinline__ void glds16(const void* g, void* l) {
    __builtin_amdgcn_global_load_lds((const g_u32*)g, (l_u32*)l, 16, 0, 0);
}

// scalar fp32 -> bf16, round-to-nearest-even
__device__ __forceinline__ u16 f2b(float f) {
    uint32_t u = __builtin_bit_cast(uint32_t, f);
    u += 0x7FFFu + ((u >> 16) & 1u);
    return (u16)(u >> 16);
}

// pack two fp32 -> two bf16 in one u32 (round-half-up)
__device__ __forceinline__ uint32_t pk2(float a, float b) {
    uint32_t ua = __builtin_bit_cast(uint32_t, a) + 0x8000u;
    uint32_t ub = __builtin_bit_cast(uint32_t, b) + 0x8000u;
    return __builtin_amdgcn_perm(ub, ua, 0x07060302u);  // lo = ua.hi16, hi = ub.hi16
}

#define MTOT  32768
#define HDIM  768
#define KDIM  2000
#define KPAD  2016

// ---------------- K0: convert weights to bf16 (proj_w padded K 2000->2016, zeros) -------
__global__ __launch_bounds__(256) void cvt_weights(
    const float* __restrict__ pw, const float* __restrict__ nw,
    u16* __restrict__ Wb, u16* __restrict__ NWb)
{
    const int h = blockIdx.x;  // 768 blocks
    const float* src = pw + (size_t)h * KDIM;
    u16* dst = Wb + (size_t)h * KPAD;
    for (int k = threadIdx.x; k < KPAD; k += 256)
        dst[k] = (k < KDIM) ? f2b(src[k]) : (u16)0;
    const float* s2 = nw + (size_t)h * HDIM;
    u16* d2 = NWb + (size_t)h * HDIM;
    for (int k = threadIdx.x; k < HDIM; k += 256)
        d2[k] = f2b(s2[k]);
}

// ---------------- K1: GEMM1 full-N strip: x[64-row panel, 0:768] = A.Wb^T + bias + gathers
// 512 threads = 8 waves, wave = 64m x 96n, acc[4][6] = 96 VGPR (launch_bounds(512,2)
// -> 256 budget, NO SPILL; R4's 1024-thread block capped VGPR at 64 and spilled).
// A fetched from HBM exactly once (fp32 -> regs -> pk2 -> swizzled ds_write).
// B staged via glds into 2-slot LDS; counted vmcnt FIFO, 7 vmem ops/slot/wave:
// {A-reg-load, B-glds x6}. Tail k>=2000: A clamped (garbage), Wb zero-padded -> 0.
__global__ __launch_bounds__(512, 2) void gemm1(
    const float* __restrict__ A, const u16* __restrict__ Wb,
    const float* __restrict__ pb,
    const int* __restrict__ i_ty, const int* __restrict__ i_la,
    const int* __restrict__ i_op, const int* __restrict__ i_in, const int* __restrict__ i_ou,
    const float* __restrict__ te, const float* __restrict__ le, const float* __restrict__ oe,
    const float* __restrict__ ie, const float* __restrict__ ooe,
    u16* __restrict__ Xb)
{
    __shared__ __align__(16) u16 As[2][64 * 32];   // 2 x  4 KB bf16
    __shared__ __align__(16) u16 Bs[2][768 * 32];  // 2 x 48 KB bf16 (104 KB total)

    const int tid = threadIdx.x;
    const int w = tid >> 6, lane = tid & 63;
    const int lm = lane & 15, quad = lane >> 4;
    const int wn = w * 96;                 // wave covers all 64 m-rows x 96 n-cols
    const int m_base = blockIdx.x * 64;    // 512 blocks, one 64-row m-panel each

    // A: lane covers fp32 16B chunk cA of row rA (coalesced 128B per 8-lane group).
    // ds_write scatters into the B-compatible XOR layout: 16B chunk s holds k-chunk
    // s^((r>>1)&3); fp32 chunk cA = k-chunk cA>>1, half cA&1.
    const int rA = w * 8 + (lane >> 3);    // 0..63
    const int cA = lane & 7;               // fp32 16B chunk 0..7
    const float* aRow = A + (size_t)(m_base + rA) * KDIM;
    const int aW = rA * 32 + (((cA >> 1) ^ ((rA >> 1) & 3)) << 3) + ((cA & 1) << 2);

    // B: 6 glds/wave, 16 rows each. glds dest linear, source XOR-swizzled.
    const u16* bSrc[6];
    int bDst[6];
#pragma unroll
    for (int t = 0; t < 6; t++) {
        const int rB = w * 96 + t * 16 + (lane >> 2);
        const int cB = (lane & 3) ^ ((rB >> 1) & 3);
        bSrc[t] = Wb + (size_t)rB * KPAD + cB * 8;
        bDst[t] = (w * 96 + t * 16) * 32;
    }

    v4f acc[4][6];
#pragma unroll
    for (int i = 0; i < 4; i++)
#pragma unroll
        for (int j = 0; j < 6; j++) acc[i][j] = (v4f){0.f, 0.f, 0.f, 0.f};

    auto lda = [&](int kb) -> float4 {
        int kf = kb * 32 + cA * 4;
        kf = (kf > 1996) ? 1996 : kf;      // clamp tail: garbage * 0-padded Wb
        return *(const float4*)(aRow + kf);
    };
    auto wrA = [&](float4 a, int sl) {
        uint2 p;
        p.x = pk2(a.x, a.y);
        p.y = pk2(a.z, a.w);
        *(uint2*)&As[sl][aW] = p;          // 8B ds_write, swizzled scatter
    };
    auto issueB = [&](int kb) {
        const int sl = kb & 1;
#pragma unroll
        for (int t = 0; t < 6; t++)
            glds16(bSrc[t] + kb * 32, &Bs[sl][bDst[t]]);
    };
    auto compute = [&](int kb) {
        const int sl = kb & 1;
        v8s af[4], bf[6];
#pragma unroll
        for (int i = 0; i < 4; i++) {
            const int r = i * 16 + lm;
            af[i] = *(const v8s*)&As[sl][r * 32 + ((quad ^ ((r >> 1) & 3)) << 3)];
        }
#pragma unroll
        for (int j = 0; j < 6; j++) {
            const int r = wn + j * 16 + lm;
            bf[j] = *(const v8s*)&Bs[sl][r * 32 + ((quad ^ ((r >> 1) & 3)) << 3)];
        }
#pragma unroll
        for (int i = 0; i < 4; i++)
#pragma unroll
            for (int j = 0; j < 6; j++)
                acc[i][j] = __builtin_amdgcn_mfma_f32_16x16x32_bf16(af[i], bf[j], acc[i][j], 0, 0, 0);
    };

    // ---- prologue: slots 0,1 in flight. FIFO: {A0, B0x6, A1, B1x6} = 14 ----
    float4 aP = lda(0);
    __builtin_amdgcn_sched_barrier(0);
    issueB(0);
    float4 aN = lda(1);
    __builtin_amdgcn_sched_barrier(0);
    issueB(1);
    asm volatile("s_waitcnt vmcnt(13)" ::: "memory");  // A0 done
    wrA(aP, 0);
    aP = aN;

    // ---- main: 63 K-steps. FIFO at top(kb): {B(kb)x6, A(kb+1), B(kb+1)x6} = 13 ----
    for (int kb = 0; kb < 61; ++kb) {
        asm volatile("s_waitcnt vmcnt(7)" ::: "memory");   // B(kb) done
        asm volatile("s_waitcnt lgkmcnt(0)" ::: "memory"); // own A(kb) ds_write done
        __builtin_amdgcn_s_barrier();
        __builtin_amdgcn_sched_barrier(0);
        compute(kb);
        __builtin_amdgcn_sched_barrier(0);
        __builtin_amdgcn_s_barrier();                      // slot kb&1 free for reuse
        aN = lda(kb + 2);
        __builtin_amdgcn_sched_barrier(0);
        issueB(kb + 2);                                    // -> 14 outstanding
        asm volatile("s_waitcnt vmcnt(13)" ::: "memory");  // A(kb+1) done
        wrA(aP, (kb + 1) & 1);
        aP = aN;
    }
    // kb = 61: outstanding {B61x6, A62, B62x6} = 13
    asm volatile("s_waitcnt vmcnt(7)" ::: "memory");
    asm volatile("s_waitcnt lgkmcnt(0)" ::: "memory");
    __builtin_amdgcn_s_barrier();
    __builtin_amdgcn_sched_barrier(0);
    compute(61);
    __builtin_amdgcn_sched_barrier(0);
    __builtin_amdgcn_s_barrier();
    asm volatile("s_waitcnt vmcnt(6)" ::: "memory");       // A62 done
    wrA(aP, 0);
    // kb = 62
    asm volatile("s_waitcnt vmcnt(0)" ::: "memory");
    asm volatile("s_waitcnt lgkmcnt(0)" ::: "memory");
    __builtin_amdgcn_s_barrier();
    __builtin_amdgcn_sched_barrier(0);
    compute(62);

    // epilogue: + proj_b + 5 table gathers, write bf16 x
#pragma unroll
    for (int i = 0; i < 4; i++) {
#pragma unroll
        for (int r = 0; r < 4; r++) {
            const int row = m_base + i * 16 + quad * 4 + r;
            const int ty = i_ty[row], la = i_la[row], op = i_op[row];
            const int di = i_in[row], doo = i_ou[row];
            const float* pte = te + (size_t)ty * HDIM;
            const float* ple = le + (size_t)la * HDIM;
            const float* poe = oe + (size_t)op * HDIM;
            const float* pie = ie + (size_t)di * HDIM;
            const float* pou = ooe + (size_t)doo * HDIM;
            u16* orow = Xb + (size_t)row * HDIM;
#pragma unroll
            for (int j = 0; j < 6; j++) {
                const int col = wn + j * 16 + lm;
                float v = acc[i][j][r] + pb[col] + pte[col] + ple[col] + poe[col] + pie[col] + pou[col];
                orow[col] = f2b(v);
            }
        }
    }
}

// ---------------- K2: GEMM2 full-N strip: y[64-row panel, 0:768] = xb.NWb^T + neg_b -----
// Same template; A = Xb already bf16 -> all-glds (waves 0-3 cover the A tile, waves
// 4-7 duplicate same src/dst to keep vmcnt uniform; identical bytes -> benign).
// 7 glds/slot/wave.
__global__ __launch_bounds__(512, 2) void gemm2(
    const u16* __restrict__ Xb, const u16* __restrict__ NWb,
    const float* __restrict__ nb, u16* __restrict__ Yb)
{
    __shared__ __align__(16) u16 As[2][64 * 32];   // 2 x  4 KB
    __shared__ __align__(16) u16 Bs[2][768 * 32];  // 2 x 48 KB

    const int tid = threadIdx.x;
    const int w = tid >> 6, lane = tid & 63;
    const int lm = lane & 15, quad = lane >> 4;
    const int wn = w * 96;
    const int m_base = blockIdx.x * 64;

    const int rA = (w & 3) * 16 + (lane >> 2);
    const int cA = (lane & 3) ^ ((rA >> 1) & 3);
    const u16* aSrc = Xb + (size_t)(m_base + rA) * HDIM + cA * 8;
    const int aDst = ((w & 3) * 16) * 32;

    const u16* bSrc[6];
    int bDst[6];
#pragma unroll
    for (int t = 0; t < 6; t++) {
        const int rB = w * 96 + t * 16 + (lane >> 2);
        const int cB = (lane & 3) ^ ((rB >> 1) & 3);
        bSrc[t] = NWb + (size_t)rB * HDIM + cB * 8;
        bDst[t] = (w * 96 + t * 16) * 32;
    }

    v4f acc[4][6];
#pragma unroll
    for (int i = 0; i < 4; i++)
#pragma unroll
        for (int j = 0; j < 6; j++) acc[i][j] = (v4f){0.f, 0.f, 0.f, 0.f};

    auto issue = [&](int kb) {
        const int sl = kb & 1;
        glds16(aSrc + kb * 32, &As[sl][aDst]);
#pragma unroll
        for (int t = 0; t < 6; t++)
            glds16(bSrc[t] + kb * 32, &Bs[sl][bDst[t]]);
    };
    auto compute = [&](int kb) {
        const int sl = kb & 1;
        v8s af[4], bf[6];
#pragma unroll
        for (int i = 0; i < 4; i++) {
            const int r = i * 16 + lm;
            af[i] = *(const v8s*)&As[sl][r * 32 + ((quad ^ ((r >> 1) & 3)) << 3)];
        }
#pragma unroll
        for (int j = 0; j < 6; j++) {
            const int r = wn + j * 16 + lm;
            bf[j] = *(const v8s*)&Bs[sl][r * 32 + ((quad ^ ((r >> 1) & 3)) << 3)];
        }
#pragma unroll
        for (int i = 0; i < 4; i++)
#pragma unroll
            for (int j = 0; j < 6; j++)
                acc[i][j] = __builtin_amdgcn_mfma_f32_16x16x32_bf16(af[i], bf[j], acc[i][j], 0, 0, 0);
    };

    // prologue: slots 0,1 in flight (14 glds/wave)
    issue(0);
    issue(1);

    // 24 K-steps; FIFO at top(kb): {slot(kb)x7, slot(kb+1)x7} = 14
    for (int kb = 0; kb < 22; ++kb) {
        asm volatile("s_waitcnt vmcnt(7)" ::: "memory");   // slot kb done
        __builtin_amdgcn_s_barrier();
        __builtin_amdgcn_sched_barrier(0);
        compute(kb);
        __builtin_amdgcn_sched_barrier(0);
        __builtin_amdgcn_s_barrier();                      // slot kb&1 free
        issue(kb + 2);
    }
    asm volatile("s_waitcnt vmcnt(7)" ::: "memory");
    __builtin_amdgcn_s_barrier();
    __builtin_amdgcn_sched_barrier(0);
    compute(22);
    __builtin_amdgcn_sched_barrier(0);
    __builtin_amdgcn_s_barrier();
    asm volatile("s_waitcnt vmcnt(0)" ::: "memory");
    __builtin_amdgcn_s_barrier();
    __builtin_amdgcn_sched_barrier(0);
    compute(23);

#pragma unroll
    for (int i = 0; i < 4; i++) {
#pragma unroll
        for (int r = 0; r < 4; r++) {
            const int row = m_base + i * 16 + quad * 4 + r;
            u16* orow = Yb + (size_t)row * HDIM;
#pragma unroll
            for (int j = 0; j < 6; j++) {
                const int col = wn + j * 16 + lm;
                orow[col] = f2b(acc[i][j][r] + nb[col]);
            }
        }
    }
}

// ---------------- K3: select (negs) + LayerNorm, one wave per row -----------------------
__global__ __launch_bounds__(256) void ln_k(
    const u16* __restrict__ Xb, const u16* __restrict__ Yb,
    const int* __restrict__ negs,
    const float* __restrict__ g, const float* __restrict__ b,
    float* __restrict__ out)
{
    const int w = threadIdx.x >> 6, lane = threadIdx.x & 63;
    const int row = blockIdx.x * 4 + w;
    const u16* src = ((negs[row] == 1) ? Yb : Xb) + (size_t)row * HDIM;

    float v[12];
    float s = 0.f, ss = 0.f;
#pragma unroll
    for (int p = 0; p < 3; p++) {
        uint2 u = *(const uint2*)(src + (p * 64 + lane) * 4);
        float f0 = __builtin_bit_cast(float, u.x << 16);
        float f1 = __builtin_bit_cast(float, u.x & 0xFFFF0000u);
        float f2 = __builtin_bit_cast(float, u.y << 16);
        float f3 = __builtin_bit_cast(float, u.y & 0xFFFF0000u);
        v[p * 4 + 0] = f0; v[p * 4 + 1] = f1; v[p * 4 + 2] = f2; v[p * 4 + 3] = f3;
        s += f0 + f1 + f2 + f3;
        ss += f0 * f0 + f1 * f1 + f2 * f2 + f3 * f3;
    }
#pragma unroll
    for (int off = 1; off < 64; off <<= 1) {
        s += __shfl_xor(s, off);
        ss += __shfl_xor(ss, off);
    }
    const float mean = s * (1.f / (float)HDIM);
    const float var = ss * (1.f / (float)HDIM) - mean * mean;
    const float rs = rsqrtf(var + 1e-12f);

    float* orow = out + (size_t)row * HDIM;
#pragma unroll
    for (int p = 0; p < 3; p++) {
        const int c0 = (p * 64 + lane) * 4;
        float4 gg = *(const float4*)(g + c0);
        float4 bb = *(const float4*)(b + c0);
        float4 o;
        o.x = (v[p * 4 + 0] - mean) * rs * gg.x + bb.x;
        o.y = (v[p * 4 + 1] - mean) * rs * gg.y + bb.y;
        o.z = (v[p * 4 + 2] - mean) * rs * gg.z + bb.z;
        o.w = (v[p * 4 + 3] - mean) * rs * gg.w + bb.w;
        *(float4*)(orow + c0) = o;
    }
}

extern "C" void kernel_launch(void* const* d_in, const int* in_sizes, int n_in,
                              void* d_out, int out_size, void* d_ws, size_t ws_size,
                              hipStream_t stream) {
    (void)in_sizes; (void)n_in; (void)out_size; (void)ws_size;
    const float* A   = (const float*)d_in[0];
    const int* i_ty  = (const int*)d_in[1];
    const int* i_la  = (const int*)d_in[2];
    const int* i_op  = (const int*)d_in[3];
    const int* i_in  = (const int*)d_in[4];
    const int* i_ou  = (const int*)d_in[5];
    const int* negs  = (const int*)d_in[6];
    const float* te  = (const float*)d_in[7];
    const float* le  = (const float*)d_in[8];
    const float* oe  = (const float*)d_in[9];
    const float* ie  = (const float*)d_in[10];
    const float* ooe = (const float*)d_in[11];
    const float* pw  = (const float*)d_in[12];
    const float* pb  = (const float*)d_in[13];
    const float* nw  = (const float*)d_in[14];
    const float* nb  = (const float*)d_in[15];
    const float* lng = (const float*)d_in[16];
    const float* lnb = (const float*)d_in[17];
    float* out = (float*)d_out;

    // workspace layout (total ~100.1 MiB)
    char* ws = (char*)d_ws;
    u16* Wb  = (u16*)ws;                                   // 768*2016*2  = 3,096,576
    u16* NWb = (u16*)(ws + 3096576);                       // 768*768*2   = 1,179,648
    u16* Xb  = (u16*)(ws + 3096576 + 1179648);             // 32768*768*2 = 50,331,648
    u16* Yb  = (u16*)(ws + 3096576 + 1179648 + 50331648);  // 50,331,648

    cvt_weights<<<768, 256, 0, stream>>>(pw, nw, Wb, NWb);
    gemm1<<<512, 512, 0, stream>>>(A, Wb, pb, i_ty, i_la, i_op, i_in, i_ou,
                                   te, le, oe, ie, ooe, Xb);
    gemm2<<<512, 512, 0, stream>>>(Xb, NWb, nb, Yb);
    ln_k<<<8192, 256, 0, stream>>>(Xb, Yb, negs, lng, lnb, out);
}

// Round 6
// 685.638 us; speedup vs baseline: 1.7015x; 1.0721x over previous
//
#include <hip/hip_runtime.h>
#include <stdint.h>

typedef unsigned short u16;
typedef short v8s __attribute__((ext_vector_type(8)));
typedef float v4f __attribute__((ext_vector_type(4)));

typedef __attribute__((address_space(1))) uint32_t g_u32;
typedef __attribute__((address_space(3))) uint32_t l_u32;

__device__ __forceinline__ void glds16(const void* g, void* l) {
    __builtin_amdgcn_global_load_lds((const g_u32*)g, (l_u32*)l, 16, 0, 0);
}
__device__ __forceinline__ u16 f2b(float f) {
    uint32_t u = __builtin_bit_cast(uint32_t, f);
    u += 0x7FFFu + ((u >> 16) & 1u);
    return (u16)(u >> 16);
}
__device__ __forceinline__ uint32_t pk2(float a, float b) {
    uint32_t ua = __builtin_bit_cast(uint32_t, a) + 0x8000u;
    uint32_t ub = __builtin_bit_cast(uint32_t, b) + 0x8000u;
    return __builtin_amdgcn_perm(ub, ua, 0x07060302u);
}

#define MTOT  32768
#define HDIM  768
#define KDIM  2000
#define KP2   2048

#define BARX do { __builtin_amdgcn_s_barrier(); __builtin_amdgcn_sched_barrier(0); } while (0)
#define VMW(n) asm volatile("s_waitcnt vmcnt(" #n ")" ::: "memory")
#define LGKM0  asm volatile("s_waitcnt lgkmcnt(0)" ::: "memory")

// ---------------- K0: weights -> bf16 (proj_w padded K 2000->2048 with zeros) -----------
__global__ __launch_bounds__(256) void cvt_weights(
    const float* __restrict__ pw, const float* __restrict__ nw,
    u16* __restrict__ Wb, u16* __restrict__ NWb)
{
    const int h = blockIdx.x;  // 768
    const float* src = pw + (size_t)h * KDIM;
    u16* dst = Wb + (size_t)h * KP2;
    for (int k = threadIdx.x; k < KP2; k += 256)
        dst[k] = (k < KDIM) ? f2b(src[k]) : (u16)0;
    const float* s2 = nw + (size_t)h * HDIM;
    u16* d2 = NWb + (size_t)h * HDIM;
    for (int k = threadIdx.x; k < HDIM; k += 256)
        d2[k] = f2b(s2[k]);
}

// ---------------- K1: GEMM1 256x256 tile, BK=64, 8-phase interleave ---------------------
// 512 thr / 8 waves (2m x 4n), wave out 128x64 = acc[8][4]. 2 LDS buffers (128 KB).
// Per phase: {4 A fp32 loads OR 2 B glds} + 12 swizzled ds_read_b128 + 16 MFMA(setprio).
// A: fp32 -> regs -> pk2 -> swizzled ds_write, 2 phases after load (vmcnt(6) counted).
// Stage targets: p0,p1 -> tile 2i+1 (buf1); p2-p5 -> 2i+2 (buf0); p6,p7 -> 2i+3 (buf1).
// All writes >=1 barrier after the stripe's last read; all reads >=4 phases after issue.
// K padded to 2048: tail A-loads clamped (garbage), Wb zero-padded -> contributes 0.
__global__ __launch_bounds__(512, 2) void gemm1(
    const float* __restrict__ A, const u16* __restrict__ Wb,
    const float* __restrict__ pb,
    const int* __restrict__ i_ty, const int* __restrict__ i_la,
    const int* __restrict__ i_op, const int* __restrict__ i_in, const int* __restrict__ i_ou,
    const float* __restrict__ te, const float* __restrict__ le, const float* __restrict__ oe,
    const float* __restrict__ ie, const float* __restrict__ ooe,
    u16* __restrict__ Xb)
{
    __shared__ __align__(16) u16 As[2][256 * 64];  // 2 x 32 KB
    __shared__ __align__(16) u16 Bs[2][256 * 64];  // 2 x 32 KB

    const int bid = blockIdx.x;                 // 384 = 128 mt x 3 nt
    const int sw = (bid & 7) * 48 + (bid >> 3); // bijective XCD swizzle (384 % 8 == 0)
    const int mt = sw / 3, nt = sw % 3;
    const int m_base = mt * 256, n_base = nt * 256;

    const int tid = threadIdx.x;
    const int w = tid >> 6, lane = tid & 63;
    const int lm = lane & 15, quad = lane >> 4;
    const int wm = (w >> 2) * 128, wn = (w & 3) * 64;

    // staging lane decomposition: 8 rows x 8 chunks(16B) per glds-round
    const int rsub = lane >> 3, csub = lane & 7;
    const int cxa = csub ^ (rsub & 7);          // source k-chunk for slot csub (XOR swizzle)
    const float* aBase = A + (size_t)(m_base + rsub) * KDIM;
    const u16* bBase = Wb + (size_t)(n_base + rsub) * KP2 + cxa * 8;

    v4f acc[8][4];
#pragma unroll
    for (int i = 0; i < 8; i++)
#pragma unroll
        for (int j = 0; j < 4; j++) acc[i][j] = (v4f){0.f, 0.f, 0.f, 0.f};

    // load one A group (G0: rows 0-63/128-191, G1: +64) -> 4 float4
    auto ldA = [&](int kt, int g, float4* r) {
        int ko = kt * 64 + cxa * 8;
        if (ko > 1992) ko = 1992;               // tail: garbage * zero-padded Wb
#pragma unroll
        for (int h = 0; h < 2; h++) {
            const float* p = aBase + (size_t)(g * 64 + w * 8 + h * 128) * KDIM + ko;
            r[h * 2 + 0] = *(const float4*)p;
            r[h * 2 + 1] = *(const float4*)(p + 4);
        }
    };
    // convert + swizzled ds_write of one A group
    auto wrA = [&](int buf, int g, const float4* r) {
#pragma unroll
        for (int h = 0; h < 2; h++) {
            const int row = g * 64 + w * 8 + h * 128 + rsub;
            int4 q;
            q.x = (int)pk2(r[h*2].x, r[h*2].y);   q.y = (int)pk2(r[h*2].z, r[h*2].w);
            q.z = (int)pk2(r[h*2+1].x, r[h*2+1].y); q.w = (int)pk2(r[h*2+1].z, r[h*2+1].w);
            *(int4*)&As[buf][row * 64 + csub * 8] = q;
        }
    };
    // stage one B stripe (S0: rows 0-31/64-95 +128..., S1: +32) via 2 glds
    auto stB = [&](int kt, int s, int buf) {
#pragma unroll
        for (int h = 0; h < 2; h++) {
            const int rowb = s * 32 + (w >> 2) * 64 + (w & 3) * 8 + h * 128;
            glds16(bBase + (size_t)rowb * KP2 + kt * 64, &Bs[buf][rowb * 64]);
        }
    };
    // one phase: quadrant (qm, qn) of buffer buf — 12 ds_read + 16 MFMA
    auto phase = [&](int buf, int qm, int qn) {
        v8s af[4][2], bf[2][2];
#pragma unroll
        for (int fi = 0; fi < 4; fi++)
#pragma unroll
            for (int ks = 0; ks < 2; ks++) {
                const int r = wm + qm * 64 + fi * 16 + lm;
                af[fi][ks] = *(const v8s*)&As[buf][r * 64 + (((ks * 4 + quad) ^ (lm & 7)) << 3)];
            }
#pragma unroll
        for (int fj = 0; fj < 2; fj++)
#pragma unroll
            for (int ks = 0; ks < 2; ks++) {
                const int r = wn + qn * 32 + fj * 16 + lm;
                bf[fj][ks] = *(const v8s*)&Bs[buf][r * 64 + (((ks * 4 + quad) ^ (lm & 7)) << 3)];
            }
        LGKM0;
        __builtin_amdgcn_sched_barrier(0);
        __builtin_amdgcn_s_setprio(1);
#pragma unroll
        for (int fi = 0; fi < 4; fi++)
#pragma unroll
            for (int fj = 0; fj < 2; fj++)
#pragma unroll
                for (int ks = 0; ks < 2; ks++)
                    acc[qm*4+fi][qn*2+fj] = __builtin_amdgcn_mfma_f32_16x16x32_bf16(
                        af[fi][ks], bf[fj][ks], acc[qm*4+fi][qn*2+fj], 0, 0, 0);
        __builtin_amdgcn_s_setprio(0);
    };

    // ---- prologue: buf0 <- tile0 (A written, B staged), buf1 <- t1 A-G0 written,
    //      t1 B-S0 staged; sPrev <- A-G1(t1) loads (written at iter0-p0) ----
    float4 r0[4], r1[4], r2[4], sPrev[4];
    ldA(0, 0, r0); ldA(0, 1, r1); ldA(1, 0, r2);   // 12 loads
    stB(0, 0, 0);                                   // B-S0(t0)
    VMW(10); wrA(0, 0, r0);
    VMW(6);  wrA(0, 1, r1);
    VMW(2);  wrA(1, 0, r2);
    stB(0, 1, 0);                                   // B-S1(t0)
    ldA(1, 1, sPrev);                               // A-G1(t1)
    stB(1, 0, 1);                                   // B-S0(t1)
    LGKM0;

    for (int it = 0; it < 16; ++it) {
        int tO1 = 2 * it + 1;
        int tE2 = 2 * it + 2; if (tE2 > 31) tE2 = 31;
        int tO3 = 2 * it + 3; if (tO3 > 31) tO3 = 31;
        float4 s0[4], s1[4], s2[4];
        // p0: compute(buf0,q00); load A-G0(tE2); write A-G1(tO1)<-sPrev
        BARX; ldA(tE2, 0, s0); VMW(6); wrA(1, 1, sPrev); phase(0, 0, 0);
        // p1: B-S1(tO1) -> buf1
        BARX; stB(tO1, 1, 1); phase(0, 0, 1);
        // p2: load A-G1(tE2); write A-G0(tE2)<-s0
        BARX; ldA(tE2, 1, s1); VMW(6); wrA(0, 0, s0); phase(0, 1, 0);
        // p3: B-S0(tE2) -> buf0
        BARX; stB(tE2, 0, 0); phase(0, 1, 1);
        // p4: load A-G0(tO3); write A-G1(tE2)<-s1
        BARX; ldA(tO3, 0, s2); VMW(6); wrA(0, 1, s1); phase(1, 0, 0);
        // p5: B-S1(tE2) -> buf0
        BARX; stB(tE2, 1, 0); phase(1, 0, 1);
        // p6: load A-G1(tO3)->sPrev; write A-G0(tO3)<-s2
        BARX; ldA(tO3, 1, sPrev); VMW(6); wrA(1, 0, s2); phase(1, 1, 0);
        // p7: B-S0(tO3) -> buf1
        BARX; stB(tO3, 0, 1); phase(1, 1, 1);
    }

    // epilogue: + proj_b + 5 table gathers, write bf16 x
#pragma unroll
    for (int i = 0; i < 8; i++) {
#pragma unroll
        for (int r = 0; r < 4; r++) {
            const int row = m_base + wm + i * 16 + quad * 4 + r;
            const int ty = i_ty[row], la = i_la[row], op = i_op[row];
            const int di = i_in[row], doo = i_ou[row];
            const float* pte = te + (size_t)ty * HDIM;
            const float* ple = le + (size_t)la * HDIM;
            const float* poe = oe + (size_t)op * HDIM;
            const float* pie = ie + (size_t)di * HDIM;
            const float* pou = ooe + (size_t)doo * HDIM;
            u16* orow = Xb + (size_t)row * HDIM;
#pragma unroll
            for (int j = 0; j < 4; j++) {
                const int col = n_base + wn + j * 16 + lm;
                float v = acc[i][j][r] + pb[col] + pte[col] + ple[col] + poe[col] + pie[col] + pou[col];
                orow[col] = f2b(v);
            }
        }
    }
}

// ---------------- K2: GEMM2 256x256 tile, 8-phase, all-glds (A = Xb bf16) ---------------
// K=768 -> 12 K-tiles, 6 iterations. Waits vmcnt(8)@p0,p4 and vmcnt(6)@p1,p5.
__global__ __launch_bounds__(512, 2) void gemm2(
    const u16* __restrict__ Xb, const u16* __restrict__ NWb,
    const float* __restrict__ nb, u16* __restrict__ Yb)
{
    __shared__ __align__(16) u16 As[2][256 * 64];
    __shared__ __align__(16) u16 Bs[2][256 * 64];

    const int bid = blockIdx.x;
    const int sw = (bid & 7) * 48 + (bid >> 3);
    const int mt = sw / 3, nt = sw % 3;
    const int m_base = mt * 256, n_base = nt * 256;

    const int tid = threadIdx.x;
    const int w = tid >> 6, lane = tid & 63;
    const int lm = lane & 15, quad = lane >> 4;
    const int wm = (w >> 2) * 128, wn = (w & 3) * 64;

    const int rsub = lane >> 3, csub = lane & 7;
    const int cxa = csub ^ (rsub & 7);
    const u16* aBase = Xb  + (size_t)(m_base + rsub) * HDIM + cxa * 8;
    const u16* bBase = NWb + (size_t)(n_base + rsub) * HDIM + cxa * 8;

    v4f acc[8][4];
#pragma unroll
    for (int i = 0; i < 8; i++)
#pragma unroll
        for (int j = 0; j < 4; j++) acc[i][j] = (v4f){0.f, 0.f, 0.f, 0.f};

    auto stA = [&](int kt, int g, int buf) {
#pragma unroll
        for (int h = 0; h < 2; h++) {
            const int rowb = g * 64 + w * 8 + h * 128;
            glds16(aBase + (size_t)rowb * HDIM + kt * 64, &As[buf][rowb * 64]);
        }
    };
    auto stB = [&](int kt, int s, int buf) {
#pragma unroll
        for (int h = 0; h < 2; h++) {
            const int rowb = s * 32 + (w >> 2) * 64 + (w & 3) * 8 + h * 128;
            glds16(bBase + (size_t)rowb * HDIM + kt * 64, &Bs[buf][rowb * 64]);
        }
    };
    auto phase = [&](int buf, int qm, int qn) {
        v8s af[4][2], bf[2][2];
#pragma unroll
        for (int fi = 0; fi < 4; fi++)
#pragma unroll
            for (int ks = 0; ks < 2; ks++) {
                const int r = wm + qm * 64 + fi * 16 + lm;
                af[fi][ks] = *(const v8s*)&As[buf][r * 64 + (((ks * 4 + quad) ^ (lm & 7)) << 3)];
            }
#pragma unroll
        for (int fj = 0; fj < 2; fj++)
#pragma unroll
            for (int ks = 0; ks < 2; ks++) {
                const int r = wn + qn * 32 + fj * 16 + lm;
                bf[fj][ks] = *(const v8s*)&Bs[buf][r * 64 + (((ks * 4 + quad) ^ (lm & 7)) << 3)];
            }
        LGKM0;
        __builtin_amdgcn_sched_barrier(0);
        __builtin_amdgcn_s_setprio(1);
#pragma unroll
        for (int fi = 0; fi < 4; fi++)
#pragma unroll
            for (int fj = 0; fj < 2; fj++)
#pragma unroll
                for (int ks = 0; ks < 2; ks++)
                    acc[qm*4+fi][qn*2+fj] = __builtin_amdgcn_mfma_f32_16x16x32_bf16(
                        af[fi][ks], bf[fj][ks], acc[qm*4+fi][qn*2+fj], 0, 0, 0);
        __builtin_amdgcn_s_setprio(0);
    };

    // prologue: t0 full (buf0) + t1 A-G0/B-S0 (buf1); t1 A-G1/B-S1 staged at iter0 p0/p1
    stA(0, 0, 0); stB(0, 0, 0); stA(0, 1, 0); stB(0, 1, 0);
    stA(1, 0, 1); stB(1, 0, 1);

    for (int it = 0; it < 6; ++it) {
        int tO1 = 2 * it + 1;
        int tE2 = 2 * it + 2; if (tE2 > 11) tE2 = 11;
        int tO3 = 2 * it + 3; if (tO3 > 11) tO3 = 11;
        BARX; VMW(8); stA(tO1, 1, 1); phase(0, 0, 0);   // p0
        BARX; VMW(6); stB(tO1, 1, 1); phase(0, 0, 1);   // p1
        BARX; stA(tE2, 0, 0); phase(0, 1, 0);           // p2
        BARX; stB(tE2, 0, 0); phase(0, 1, 1);           // p3
        BARX; VMW(8); stA(tE2, 1, 0); phase(1, 0, 0);   // p4
        BARX; VMW(6); stB(tE2, 1, 0); phase(1, 0, 1);   // p5
        BARX; stA(tO3, 0, 1); phase(1, 1, 0);           // p6
        BARX; stB(tO3, 0, 1); phase(1, 1, 1);           // p7
    }

#pragma unroll
    for (int i = 0; i < 8; i++) {
#pragma unroll
        for (int r = 0; r < 4; r++) {
            const int row = m_base + wm + i * 16 + quad * 4 + r;
            u16* orow = Yb + (size_t)row * HDIM;
#pragma unroll
            for (int j = 0; j < 4; j++) {
                const int col = n_base + wn + j * 16 + lm;
                orow[col] = f2b(acc[i][j][r] + nb[col]);
            }
        }
    }
}

// ---------------- K3: select (negs) + LayerNorm, one wave per row -----------------------
__global__ __launch_bounds__(256) void ln_k(
    const u16* __restrict__ Xb, const u16* __restrict__ Yb,
    const int* __restrict__ negs,
    const float* __restrict__ g, const float* __restrict__ b,
    float* __restrict__ out)
{
    const int w = threadIdx.x >> 6, lane = threadIdx.x & 63;
    const int row = blockIdx.x * 4 + w;
    const u16* src = ((negs[row] == 1) ? Yb : Xb) + (size_t)row * HDIM;

    float v[12];
    float s = 0.f, ss = 0.f;
#pragma unroll
    for (int p = 0; p < 3; p++) {
        uint2 u = *(const uint2*)(src + (p * 64 + lane) * 4);
        float f0 = __builtin_bit_cast(float, u.x << 16);
        float f1 = __builtin_bit_cast(float, u.x & 0xFFFF0000u);
        float f2 = __builtin_bit_cast(float, u.y << 16);
        float f3 = __builtin_bit_cast(float, u.y & 0xFFFF0000u);
        v[p * 4 + 0] = f0; v[p * 4 + 1] = f1; v[p * 4 + 2] = f2; v[p * 4 + 3] = f3;
        s += f0 + f1 + f2 + f3;
        ss += f0 * f0 + f1 * f1 + f2 * f2 + f3 * f3;
    }
#pragma unroll
    for (int off = 1; off < 64; off <<= 1) {
        s += __shfl_xor(s, off);
        ss += __shfl_xor(ss, off);
    }
    const float mean = s * (1.f / (float)HDIM);
    const float var = ss * (1.f / (float)HDIM) - mean * mean;
    const float rs = rsqrtf(var + 1e-12f);

    float* orow = out + (size_t)row * HDIM;
#pragma unroll
    for (int p = 0; p < 3; p++) {
        const int c0 = (p * 64 + lane) * 4;
        float4 gg = *(const float4*)(g + c0);
        float4 bb = *(const float4*)(b + c0);
        float4 o;
        o.x = (v[p * 4 + 0] - mean) * rs * gg.x + bb.x;
        o.y = (v[p * 4 + 1] - mean) * rs * gg.y + bb.y;
        o.z = (v[p * 4 + 2] - mean) * rs * gg.z + bb.z;
        o.w = (v[p * 4 + 3] - mean) * rs * gg.w + bb.w;
        *(float4*)(orow + c0) = o;
    }
}

extern "C" void kernel_launch(void* const* d_in, const int* in_sizes, int n_in,
                              void* d_out, int out_size, void* d_ws, size_t ws_size,
                              hipStream_t stream) {
    (void)in_sizes; (void)n_in; (void)out_size; (void)ws_size;
    const float* A   = (const float*)d_in[0];
    const int* i_ty  = (const int*)d_in[1];
    const int* i_la  = (const int*)d_in[2];
    const int* i_op  = (const int*)d_in[3];
    const int* i_in  = (const int*)d_in[4];
    const int* i_ou  = (const int*)d_in[5];
    const int* negs  = (const int*)d_in[6];
    const float* te  = (const float*)d_in[7];
    const float* le  = (const float*)d_in[8];
    const float* oe  = (const float*)d_in[9];
    const float* ie  = (const float*)d_in[10];
    const float* ooe = (const float*)d_in[11];
    const float* pw  = (const float*)d_in[12];
    const float* pb  = (const float*)d_in[13];
    const float* nw  = (const float*)d_in[14];
    const float* nb  = (const float*)d_in[15];
    const float* lng = (const float*)d_in[16];
    const float* lnb = (const float*)d_in[17];
    float* out = (float*)d_out;

    // workspace layout (~100.1 MiB)
    char* ws = (char*)d_ws;
    u16* Wb  = (u16*)ws;                                   // 768*2048*2  = 3,145,728
    u16* NWb = (u16*)(ws + 3145728);                       // 768*768*2   = 1,179,648
    u16* Xb  = (u16*)(ws + 3145728 + 1179648);             // 32768*768*2 = 50,331,648
    u16* Yb  = (u16*)(ws + 3145728 + 1179648 + 50331648);  // 50,331,648

    cvt_weights<<<768, 256, 0, stream>>>(pw, nw, Wb, NWb);
    gemm1<<<384, 512, 0, stream>>>(A, Wb, pb, i_ty, i_la, i_op, i_in, i_ou,
                                   te, le, oe, ie, ooe, Xb);
    gemm2<<<384, 512, 0, stream>>>(Xb, NWb, nb, Yb);
    ln_k<<<8192, 256, 0, stream>>>(Xb, Yb, negs, lng, lnb, out);
}